// Round 6
// baseline (150.591 us; speedup 1.0000x reference)
//
#include <hip/hip_runtime.h>

// SupConLoss on MI355X. features: [4096, 2, 128] fp32; labels: [4096] int; out: 1 f32.
//
// R12 changes vs R11 (negsum was 44.8 us, MfmaUtil 14%, VALUBusy 45% -- latency
// bound on a 2-barrier-per-64-col-tile structure):
//  - k_negsum: NO LDS, NO barriers, NO labels. B-fragments read directly from
//    global (nf is 2 MB -> L2-resident; guide: don't LDS-stage what L2 fits).
//    Straight-line kernel: A-frags in regs, loop 8 col-tiles, full row sums
//    (no neg mask) -> neg_part[ch][row]. Epilogue per element: mul+exp+add
//    (was mul+exp+cmp+cndmask+add + LDS label read).
//  - k_loss: computes same-class column sums (incl. self) from its own MFMA
//    pass and subtracts: neg[j] = full[j] - same[j]. Wave w owns column-tile
//    tj=w; pass 1 accumulates same[j] over all row-tiles, pass 2 recomputes
//    acc (deterministic, bit-identical) and emits terms
//    logit - log(neg[j] + e). Self term e_jj bit-identical between negsum
//    and k_loss (same bf16 inputs, same MFMA s-order), so the dominant
//    exp(1/0.07)~1.6e6 cancels exactly; residual f32 error ~ulp(1.6M) on a
//    ~3e4 result -> ~4e-6 relative, invisible in the final scalar.
//
// ws layout: nf (2 MB) | neg_part 16x8192 f32 (512 KB) | total f32 | done u32
//            | counts 100 | offsets 101 | classIdx 4096

#define BATCH 4096
#define NN    8192
#define DD    128
#define NCLS  100
#define MAXR  192
#define NCHUNK  16        // column chunks of 512 (8 col-tiles of 64)
#define SCALE (1.0f / 0.07f)
#define K2    (SCALE * 1.44269504088896340736f)   // SCALE * log2(e)

typedef __attribute__((ext_vector_type(8))) short bf16x8;
typedef __attribute__((ext_vector_type(4))) float f32x4;

__device__ __forceinline__ unsigned short f2bf(float f) {
    unsigned u = __float_as_uint(f);
    u += 0x7FFF + ((u >> 16) & 1);
    return (unsigned short)(u >> 16);
}

// blocks 0..2047: normalize; block 0 also zeroes total/done
// block 2048:     label bucketing (histogram, offsets, member scatter)
__global__ __launch_bounds__(256) void k_norm_bucket(
        const float* __restrict__ feat, unsigned short* __restrict__ nf,
        unsigned* __restrict__ zeroTD,
        const int* __restrict__ labels, int* __restrict__ counts,
        int* __restrict__ offsets, int* __restrict__ classIdx) {
    __shared__ int cnt[NCLS], off[NCLS], cur[NCLS];

    if (blockIdx.x < NN / 4) {
        if (blockIdx.x == 0 && threadIdx.x < 2) zeroTD[threadIdx.x] = 0u;  // total, done
        int wave = threadIdx.x >> 6, lane = threadIdx.x & 63;
        int row = blockIdx.x * 4 + wave;
        int v = row >> 12, b = row & (BATCH - 1);
        const float2* src = (const float2*)(feat + ((size_t)b * 2 + v) * DD);
        float2 x = src[lane];
        float ss = x.x * x.x + x.y * x.y;
        #pragma unroll
        for (int m = 32; m >= 1; m >>= 1) ss += __shfl_xor(ss, m, 64);
        float inv = rsqrtf(ss);
        ushort2 o;
        o.x = f2bf(x.x * inv);
        o.y = f2bf(x.y * inv);
        ((ushort2*)(nf + (size_t)row * DD))[lane] = o;
        return;
    }

    // ---- bucket path (single block, 256 threads) ----
    int tid = threadIdx.x;
    if (tid < NCLS) cnt[tid] = 0;
    __syncthreads();
    for (int b = tid; b < BATCH; b += 256) atomicAdd(&cnt[labels[b]], 1);
    __syncthreads();
    if (tid < NCLS) {
        int a = 0;
        for (int k = 0; k < tid; ++k) a += cnt[k];   // lockstep LDS broadcast
        off[tid] = a;
        cur[tid] = 0;
        counts[tid] = cnt[tid];
        offsets[tid] = a;
    }
    if (tid == 0) offsets[NCLS] = BATCH;
    __syncthreads();
    for (int b = tid; b < BATCH; b += 256) {
        int l = labels[b];
        int p = atomicAdd(&cur[l], 1);
        classIdx[off[l] + p] = b;
    }
}

// ---- pass 1 (no LDS, no barriers, no mask): block (bi, ch) computes, for its
// 128 rows, full[i] partial = sum_j exp(logit_ij) over cols [ch*512, +512),
// B-fragments loaded directly from L2-resident nf. ----
__global__ __launch_bounds__(256, 4) void k_negsum(
        const unsigned short* __restrict__ nf,
        float* __restrict__ neg_part) {
    int blk = blockIdx.x;
    int bi = blk >> 4;          // 0..63   row block (128 rows)
    int ch = blk & 15;          // 0..15   column chunk (512 cols)

    int tid = threadIdx.x, wave = tid >> 6, lane = tid & 63;
    int q = lane >> 4, nq = lane & 15;
    int rowW = bi * 128 + wave * 32;           // wave's 32-row base
    const bf16x8* nfv = (const bf16x8*)nf;

    // A frags (8): direct global, once per block
    bf16x8 aF[2][4];
    #pragma unroll
    for (int rs = 0; rs < 2; ++rs) {
        int r = rowW + rs * 16 + nq;
        #pragma unroll
        for (int s = 0; s < 4; ++s) aF[rs][s] = nfv[r * 16 + s * 4 + q];
    }
    float rowsum[2][4];
    #pragma unroll
    for (int rs = 0; rs < 2; ++rs)
        #pragma unroll
        for (int rr = 0; rr < 4; ++rr) rowsum[rs][rr] = 0.0f;

    for (int ct = 0; ct < 8; ++ct) {
        int colB = ch * 512 + ct * 64;

        f32x4 acc[2][4];
        #pragma unroll
        for (int rs = 0; rs < 2; ++rs)
            #pragma unroll
            for (int cs = 0; cs < 4; ++cs) acc[rs][cs] = (f32x4){0.f, 0.f, 0.f, 0.f};

        #pragma unroll
        for (int s = 0; s < 4; ++s) {
            bf16x8 bF[4];
            #pragma unroll
            for (int cs = 0; cs < 4; ++cs)
                bF[cs] = nfv[(colB + cs * 16 + nq) * 16 + s * 4 + q];
            #pragma unroll
            for (int rs = 0; rs < 2; ++rs)
                #pragma unroll
                for (int cs = 0; cs < 4; ++cs)
                    acc[rs][cs] = __builtin_amdgcn_mfma_f32_16x16x32_bf16(
                        aF[rs][s], bF[cs], acc[rs][cs], 0, 0, 0);
        }

        // C/D layout: col = lane&15, row = (lane>>4)*4 + reg
        #pragma unroll
        for (int cs = 0; cs < 4; ++cs)
            #pragma unroll
            for (int rs = 0; rs < 2; ++rs)
                #pragma unroll
                for (int rr = 0; rr < 4; ++rr)
                    rowsum[rs][rr] += exp2f(acc[rs][cs][rr] * K2);
    }

    // reduce over nq (col groups) and plain-store the partial
    #pragma unroll
    for (int rs = 0; rs < 2; ++rs)
        #pragma unroll
        for (int rr = 0; rr < 4; ++rr) {
            float vsum = rowsum[rs][rr];
            vsum += __shfl_xor(vsum, 1, 64);
            vsum += __shfl_xor(vsum, 2, 64);
            vsum += __shfl_xor(vsum, 4, 64);
            vsum += __shfl_xor(vsum, 8, 64);
            if (nq == 0) neg_part[ch * NN + rowW + rs * 16 + q * 4 + rr] = vsum;
        }
}

// ---- pass 2: per-class MFMA; computes same-class column sums and emits
// terms with neg[j] = full[j] - same[j]. Wave w owns column-tile tj=w. ----
__global__ __launch_bounds__(256) void k_loss(
        const unsigned short* __restrict__ nf,
        const int* __restrict__ counts, const int* __restrict__ offsets,
        const int* __restrict__ classIdx,
        const float* __restrict__ neg_part,
        float* __restrict__ total, unsigned* __restrict__ done,
        float* __restrict__ out) {
    __shared__ __attribute__((aligned(16))) unsigned short s_feat[MAXR * 128]; // 48 KB
    __shared__ int s_rows[MAXR];
    __shared__ float s_full[MAXR];
    __shared__ float red[4];

    int c = blockIdx.x;
    int m = counts[c], off = offsets[c];
    int twoM = 2 * m; if (twoM > MAXR) twoM = MAXR;
    int tid = threadIdx.x, wave = tid >> 6, lane = tid & 63;
    int q = lane >> 4, nq = lane & 15;

    for (int r = tid; r < twoM; r += 256) {
        int b = classIdx[off + (r < m ? r : r - m)];
        int row = (r < m) ? b : b + BATCH;
        s_rows[r] = row;
        float ns = 0.0f;
        #pragma unroll
        for (int chp = 0; chp < NCHUNK; ++chp) ns += neg_part[chp * NN + row];
        s_full[r] = ns;
    }
    __syncthreads();    // s_rows ready before gather staging

    int ntile = (twoM + 63) >> 6;            // 1..3
    int nchunk = ntile * 64 * 16;
    // gather-stage rows (clamped: r>=twoM duplicates last row; masked later)
    for (int widx = wave; widx * 64 < nchunk; widx += 4) {
        int chunkIdx = widx * 64 + lane;
        int r = chunkIdx >> 4, cS = chunkIdx & 15;
        int cG = cS ^ (r & 15);
        int rc = r < twoM ? r : twoM - 1;
        const unsigned short* gp = nf + (size_t)s_rows[rc] * DD + cG * 8;
        unsigned short* lp = s_feat + (size_t)widx * 512;
        __builtin_amdgcn_global_load_lds(
            (const __attribute__((address_space(1))) void*)gp,
            (__attribute__((address_space(3))) void*)lp, 16, 0, 0);
    }
    __syncthreads();

    const char* sB = (const char*)s_feat;
    float partial = 0.0f;
    int tj = wave;                           // wave owns one column-tile
    if (tj < ntile) {
        // B frags for this wave's columns, hoisted (16 ds_read_b128)
        bf16x8 bF[4][4];                     // [cs][s]
        #pragma unroll
        for (int cs = 0; cs < 4; ++cs) {
            int rB = tj * 64 + cs * 16 + nq;
            #pragma unroll
            for (int s = 0; s < 4; ++s) {
                int slot = rB * 16 + ((s * 4 + q) ^ nq);
                bF[cs][s] = *(const bf16x8*)(sB + slot * 16);
            }
        }

        // ---- pass 1: same-class column sums (over all real rows, incl self) ----
        float samec[4] = {0.f, 0.f, 0.f, 0.f};
        for (int ti = 0; ti < ntile; ++ti) {
            f32x4 acc[4][4];
            #pragma unroll
            for (int rs = 0; rs < 4; ++rs)
                #pragma unroll
                for (int cs = 0; cs < 4; ++cs) acc[rs][cs] = (f32x4){0.f, 0.f, 0.f, 0.f};
            #pragma unroll
            for (int s = 0; s < 4; ++s) {
                bf16x8 aF[4];
                #pragma unroll
                for (int rs = 0; rs < 4; ++rs) {
                    int rA = ti * 64 + rs * 16 + nq;
                    int slot = rA * 16 + ((s * 4 + q) ^ nq);
                    aF[rs] = *(const bf16x8*)(sB + slot * 16);
                }
                #pragma unroll
                for (int rs = 0; rs < 4; ++rs)
                    #pragma unroll
                    for (int cs = 0; cs < 4; ++cs)
                        acc[rs][cs] = __builtin_amdgcn_mfma_f32_16x16x32_bf16(
                            aF[rs], bF[cs][s], acc[rs][cs], 0, 0, 0);
            }
            #pragma unroll
            for (int cs = 0; cs < 4; ++cs)
                #pragma unroll
                for (int rs = 0; rs < 4; ++rs)
                    #pragma unroll
                    for (int rr = 0; rr < 4; ++rr) {
                        int p = ti * 64 + rs * 16 + q * 4 + rr;
                        float e = exp2f(acc[rs][cs][rr] * K2);
                        samec[cs] += (p < twoM) ? e : 0.0f;
                    }
        }
        // complete column sums across q groups
        #pragma unroll
        for (int cs = 0; cs < 4; ++cs) {
            samec[cs] += __shfl_xor(samec[cs], 16, 64);
            samec[cs] += __shfl_xor(samec[cs], 32, 64);
        }
        // neg[col] = full[col] - same[col]
        float negc[4];
        #pragma unroll
        for (int cs = 0; cs < 4; ++cs) {
            int qq = tj * 64 + cs * 16 + nq;
            negc[cs] = s_full[qq < twoM ? qq : 0] - samec[cs];
        }

        // ---- pass 2: recompute acc (bit-identical) and emit terms ----
        for (int ti = 0; ti < ntile; ++ti) {
            f32x4 acc[4][4];
            #pragma unroll
            for (int rs = 0; rs < 4; ++rs)
                #pragma unroll
                for (int cs = 0; cs < 4; ++cs) acc[rs][cs] = (f32x4){0.f, 0.f, 0.f, 0.f};
            #pragma unroll
            for (int s = 0; s < 4; ++s) {
                bf16x8 aF[4];
                #pragma unroll
                for (int rs = 0; rs < 4; ++rs) {
                    int rA = ti * 64 + rs * 16 + nq;
                    int slot = rA * 16 + ((s * 4 + q) ^ nq);
                    aF[rs] = *(const bf16x8*)(sB + slot * 16);
                }
                #pragma unroll
                for (int rs = 0; rs < 4; ++rs)
                    #pragma unroll
                    for (int cs = 0; cs < 4; ++cs)
                        acc[rs][cs] = __builtin_amdgcn_mfma_f32_16x16x32_bf16(
                            aF[rs], bF[cs][s], acc[rs][cs], 0, 0, 0);
            }
            #pragma unroll
            for (int cs = 0; cs < 4; ++cs) {
                int qq = tj * 64 + cs * 16 + nq;
                #pragma unroll
                for (int rs = 0; rs < 4; ++rs)
                    #pragma unroll
                    for (int rr = 0; rr < 4; ++rr) {
                        int p = ti * 64 + rs * 16 + q * 4 + rr;
                        bool valid = (p < twoM) && (qq < twoM) && (p != qq);
                        float logit = acc[rs][cs][rr] * SCALE;
                        float e = __expf(logit);
                        float term = logit - __logf(negc[cs] + e);
                        partial += valid ? term : 0.0f;
                    }
            }
        }
    }

    #pragma unroll
    for (int mm = 32; mm >= 1; mm >>= 1) partial += __shfl_xor(partial, mm, 64);
    if (lane == 0) red[wave] = partial;
    __syncthreads();
    if (tid == 0) {
        atomicAdd(total, red[0] + red[1] + red[2] + red[3]);
        __threadfence();
        unsigned prev = __hip_atomic_fetch_add(done, 1u, __ATOMIC_ACQ_REL,
                                               __HIP_MEMORY_SCOPE_AGENT);
        if (prev == (unsigned)(NCLS - 1)) {
            float tot = __hip_atomic_load(total, __ATOMIC_ACQUIRE,
                                          __HIP_MEMORY_SCOPE_AGENT);
            out[0] = -tot * (1.0f / (float)NN);
        }
    }
}

extern "C" void kernel_launch(void* const* d_in, const int* in_sizes, int n_in,
                              void* d_out, int out_size, void* d_ws, size_t ws_size,
                              hipStream_t stream) {
    const float* feat = (const float*)d_in[0];
    const int* labels = (const int*)d_in[1];
    unsigned short* nf = (unsigned short*)d_ws;
    float* neg_part = (float*)((char*)d_ws + (size_t)NN * DD * sizeof(unsigned short));
    float* total    = neg_part + NCHUNK * NN; // 1
    unsigned* done  = (unsigned*)(total + 1); // 1
    int* counts     = (int*)(done + 1);       // 100
    int* offsets    = counts + NCLS;          // 101
    int* classIdx   = offsets + NCLS + 1;     // 4096
    float* out = (float*)d_out;

    hipLaunchKernelGGL(k_norm_bucket, dim3(NN / 4 + 1), dim3(256), 0, stream,
                       feat, nf, (unsigned*)total, labels, counts, offsets, classIdx);
    hipLaunchKernelGGL(k_negsum, dim3(64 * NCHUNK), dim3(256), 0, stream, nf, neg_part);
    hipLaunchKernelGGL(k_loss, dim3(NCLS), dim3(256), 0, stream,
                       nf, counts, offsets, classIdx, neg_part, total, done, out);
}

// Round 7
// 115.532 us; speedup vs baseline: 1.3035x; 1.3035x over previous
//
#include <hip/hip_runtime.h>

// SupConLoss on MI355X. features: [4096, 2, 128] fp32; labels: [4096] int; out: 1 f32.
//
// R13 changes vs R12 (direct-L2 negsum regressed 44.8->71.3 us; reverted to
// staged structure) and vs R11 (whose counters showed the epilogue VALU is
// the dominant pipe: 20 us of VALUBusy in negsum):
//  - k_negsum exploits SYMMETRY of the logit matrix, atomic-free:
//    grid = 2080 upper-triangle 128x128 tiles (bi<=bj), R9's staged dbuf
//    LDS pipeline per tile. Row sums (reg reduce) -> part[bj][rows of bi];
//    col sums (LDS ds_add_f32 reduce) -> part[bi][cols of bj]; diag blocks
//    write row sums only (their col sums are symmetric duplicates).
//    Every part[k][r] slot written exactly once -> no zeroing, no atomics.
//    Halves exp count (67M->34M) AND MFMA (17.2->8.7 GF) vs R9/R11.
//  - negsum stays label-free (R12's proven trick): k_loss subtracts
//    same-class column sums (incl. bit-identical self term) from
//    full[r] = sum_{k<64} part[k][r].
//  - k_loss: R12's version, gather loop over 64 partials.
//
// ws layout: nf (2 MB) | part 64x8192 f32 (2 MB) | total f32 | done u32
//            | counts 100 | offsets 101 | classIdx 4096

#define BATCH 4096
#define NN    8192
#define DD    128
#define NCLS  100
#define MAXR  192
#define NPART 64          // one partial per 128-row/col block
#define NBLK  64          // 8192 / 128
#define NSEG  2080        // 64*65/2 upper-triangle tiles
#define SCALE (1.0f / 0.07f)
#define K2    (SCALE * 1.44269504088896340736f)   // SCALE * log2(e)

typedef __attribute__((ext_vector_type(8))) short bf16x8;
typedef __attribute__((ext_vector_type(4))) float f32x4;

__device__ __forceinline__ unsigned short f2bf(float f) {
    unsigned u = __float_as_uint(f);
    u += 0x7FFF + ((u >> 16) & 1);
    return (unsigned short)(u >> 16);
}

// blocks 0..2047: normalize; block 0 also zeroes total/done
// block 2048:     label bucketing (histogram, offsets, member scatter)
__global__ __launch_bounds__(256) void k_norm_bucket(
        const float* __restrict__ feat, unsigned short* __restrict__ nf,
        unsigned* __restrict__ zeroTD,
        const int* __restrict__ labels, int* __restrict__ counts,
        int* __restrict__ offsets, int* __restrict__ classIdx) {
    __shared__ int cnt[NCLS], off[NCLS], cur[NCLS];

    if (blockIdx.x < NN / 4) {
        if (blockIdx.x == 0 && threadIdx.x < 2) zeroTD[threadIdx.x] = 0u;  // total, done
        int wave = threadIdx.x >> 6, lane = threadIdx.x & 63;
        int row = blockIdx.x * 4 + wave;
        int v = row >> 12, b = row & (BATCH - 1);
        const float2* src = (const float2*)(feat + ((size_t)b * 2 + v) * DD);
        float2 x = src[lane];
        float ss = x.x * x.x + x.y * x.y;
        #pragma unroll
        for (int m = 32; m >= 1; m >>= 1) ss += __shfl_xor(ss, m, 64);
        float inv = rsqrtf(ss);
        ushort2 o;
        o.x = f2bf(x.x * inv);
        o.y = f2bf(x.y * inv);
        ((ushort2*)(nf + (size_t)row * DD))[lane] = o;
        return;
    }

    // ---- bucket path (single block, 256 threads) ----
    int tid = threadIdx.x;
    if (tid < NCLS) cnt[tid] = 0;
    __syncthreads();
    for (int b = tid; b < BATCH; b += 256) atomicAdd(&cnt[labels[b]], 1);
    __syncthreads();
    if (tid < NCLS) {
        int a = 0;
        for (int k = 0; k < tid; ++k) a += cnt[k];   // lockstep LDS broadcast
        off[tid] = a;
        cur[tid] = 0;
        counts[tid] = cnt[tid];
        offsets[tid] = a;
    }
    if (tid == 0) offsets[NCLS] = BATCH;
    __syncthreads();
    for (int b = tid; b < BATCH; b += 256) {
        int l = labels[b];
        int p = atomicAdd(&cur[l], 1);
        classIdx[off[l] + p] = b;
    }
}

// stage one 64-row x 128-col bf16 half-tile into LDS buffer `buf` (16 KB),
// XOR-swizzled: LDS slot (r, cS) holds global chunk (r, cS ^ (r&15)).
__device__ __forceinline__ void stage_half(unsigned short* smem, const unsigned short* nf,
                                           int buf, int hrow, int wave, int lane) {
    #pragma unroll
    for (int it = 0; it < 4; ++it) {
        int widx = wave * 4 + it;              // 0..15
        int chunkIdx = widx * 64 + lane;       // 0..1023
        int r = chunkIdx >> 4, cS = chunkIdx & 15;
        int cG = cS ^ (r & 15);
        const unsigned short* gp = nf + (size_t)(hrow + r) * DD + cG * 8;
        unsigned short* lp = smem + (size_t)buf * 8192 + (size_t)widx * 512;
        __builtin_amdgcn_global_load_lds(
            (const __attribute__((address_space(1))) void*)gp,
            (__attribute__((address_space(3))) void*)lp, 16, 0, 0);
    }
}

// ---- pass 1 (symmetric, atomic-free, label-free): tile (bi,bj), bi<=bj.
// Row sums of exp(logit) over the 128 cols of bj -> part[bj][rows of bi];
// col sums over the 128 rows of bi -> part[bi][cols of bj] (off-diag only).
__global__ __launch_bounds__(256, 4) void k_negsum(
        const unsigned short* __restrict__ nf,
        float* __restrict__ part) {
    __shared__ __attribute__((aligned(16))) unsigned short smem[2 * 64 * 128];  // 32 KB
    __shared__ float s_colacc[128];                                             // 512 B

    // triangular unrank: g -> (bi, bj)
    int g = blockIdx.x, bi = 0;
    for (;;) {
        int n = NBLK - bi;
        if (g < n) break;
        g -= n; ++bi;
    }
    int bj = bi + g;
    bool diag = (bi == bj);

    int tid = threadIdx.x, wave = tid >> 6, lane = tid & 63;
    int q = lane >> 4, nq = lane & 15;
    int rowW = bi * 128 + wave * 32;           // wave's 32-row base
    const bf16x8* nfv = (const bf16x8*)nf;

    if (tid < 128) s_colacc[tid] = 0.0f;

    // A frags (8): direct global (L2-resident), once per block
    bf16x8 aF[2][4];
    #pragma unroll
    for (int rs = 0; rs < 2; ++rs) {
        int r = rowW + rs * 16 + nq;
        #pragma unroll
        for (int s = 0; s < 4; ++s) aF[rs][s] = nfv[r * 16 + s * 4 + q];
    }
    float rowsum[2][4];
    #pragma unroll
    for (int rs = 0; rs < 2; ++rs)
        #pragma unroll
        for (int rr = 0; rr < 4; ++rr) rowsum[rs][rr] = 0.0f;

    stage_half(smem, nf, 0, bj * 128, wave, lane);

    for (int ht = 0; ht < 2; ++ht) {
        __syncthreads();                       // buf ht ready (also covers colacc zero)
        if (ht == 0) stage_half(smem, nf, 1, bj * 128 + 64, wave, lane);
        const char* sB = (const char*)(smem + (size_t)ht * 8192);

        f32x4 acc[2][4];
        #pragma unroll
        for (int rs = 0; rs < 2; ++rs)
            #pragma unroll
            for (int cs = 0; cs < 4; ++cs) acc[rs][cs] = (f32x4){0.f, 0.f, 0.f, 0.f};
        #pragma unroll
        for (int s = 0; s < 4; ++s) {
            bf16x8 bF[4];
            #pragma unroll
            for (int cs = 0; cs < 4; ++cs) {
                int rB = cs * 16 + nq;                       // local row in half-tile
                int slot = rB * 16 + ((s * 4 + q) ^ nq);
                bF[cs] = *(const bf16x8*)(sB + slot * 16);
            }
            #pragma unroll
            for (int rs = 0; rs < 2; ++rs)
                #pragma unroll
                for (int cs = 0; cs < 4; ++cs)
                    acc[rs][cs] = __builtin_amdgcn_mfma_f32_16x16x32_bf16(
                        aF[rs][s], bF[cs], acc[rs][cs], 0, 0, 0);
        }

        // C/D layout: col = lane&15, row = (lane>>4)*4 + reg
        #pragma unroll
        for (int cs = 0; cs < 4; ++cs) {
            float colsum = 0.0f;
            #pragma unroll
            for (int rs = 0; rs < 2; ++rs)
                #pragma unroll
                for (int rr = 0; rr < 4; ++rr) {
                    float e = exp2f(acc[rs][cs][rr] * K2);
                    rowsum[rs][rr] += e;
                    colsum += e;
                }
            if (!diag) {
                colsum += __shfl_xor(colsum, 16, 64);
                colsum += __shfl_xor(colsum, 32, 64);
                if (q == 0) atomicAdd(&s_colacc[ht * 64 + cs * 16 + nq], colsum);
            }
        }
    }

    // row partials: reduce over nq groups, store to part[bj][row]
    #pragma unroll
    for (int rs = 0; rs < 2; ++rs)
        #pragma unroll
        for (int rr = 0; rr < 4; ++rr) {
            float vsum = rowsum[rs][rr];
            vsum += __shfl_xor(vsum, 1, 64);
            vsum += __shfl_xor(vsum, 2, 64);
            vsum += __shfl_xor(vsum, 4, 64);
            vsum += __shfl_xor(vsum, 8, 64);
            if (nq == 0) part[(size_t)bj * NN + rowW + rs * 16 + q * 4 + rr] = vsum;
        }

    // col partials: part[bi][cols of bj]
    if (!diag) {
        __syncthreads();                       // all waves' ds_add_f32 done
        if (tid < 128) part[(size_t)bi * NN + bj * 128 + tid] = s_colacc[tid];
    }
}

// ---- pass 2: per-class MFMA; same-class column sums subtracted from
// full[j] = sum_k part[k][j]. Wave w owns column-tile tj=w. ----
__global__ __launch_bounds__(256) void k_loss(
        const unsigned short* __restrict__ nf,
        const int* __restrict__ counts, const int* __restrict__ offsets,
        const int* __restrict__ classIdx,
        const float* __restrict__ part,
        float* __restrict__ total, unsigned* __restrict__ done,
        float* __restrict__ out) {
    __shared__ __attribute__((aligned(16))) unsigned short s_feat[MAXR * 128]; // 48 KB
    __shared__ int s_rows[MAXR];
    __shared__ float s_full[MAXR];
    __shared__ float red[4];

    int c = blockIdx.x;
    int m = counts[c], off = offsets[c];
    int twoM = 2 * m; if (twoM > MAXR) twoM = MAXR;
    int tid = threadIdx.x, wave = tid >> 6, lane = tid & 63;
    int q = lane >> 4, nq = lane & 15;

    for (int r = tid; r < twoM; r += 256) {
        int b = classIdx[off + (r < m ? r : r - m)];
        int row = (r < m) ? b : b + BATCH;
        s_rows[r] = row;
        float ns = 0.0f;
        #pragma unroll 16
        for (int kp = 0; kp < NPART; ++kp) ns += part[(size_t)kp * NN + row];
        s_full[r] = ns;
    }
    __syncthreads();    // s_rows ready before gather staging

    int ntile = (twoM + 63) >> 6;            // 1..3
    int nchunk = ntile * 64 * 16;
    // gather-stage rows (clamped: r>=twoM duplicates last row; masked later)
    for (int widx = wave; widx * 64 < nchunk; widx += 4) {
        int chunkIdx = widx * 64 + lane;
        int r = chunkIdx >> 4, cS = chunkIdx & 15;
        int cG = cS ^ (r & 15);
        int rc = r < twoM ? r : twoM - 1;
        const unsigned short* gp = nf + (size_t)s_rows[rc] * DD + cG * 8;
        unsigned short* lp = s_feat + (size_t)widx * 512;
        __builtin_amdgcn_global_load_lds(
            (const __attribute__((address_space(1))) void*)gp,
            (__attribute__((address_space(3))) void*)lp, 16, 0, 0);
    }
    __syncthreads();

    const char* sB = (const char*)s_feat;
    float partial = 0.0f;
    int tj = wave;                           // wave owns one column-tile
    if (tj < ntile) {
        // B frags for this wave's columns, hoisted (16 ds_read_b128)
        bf16x8 bF[4][4];                     // [cs][s]
        #pragma unroll
        for (int cs = 0; cs < 4; ++cs) {
            int rB = tj * 64 + cs * 16 + nq;
            #pragma unroll
            for (int s = 0; s < 4; ++s) {
                int slot = rB * 16 + ((s * 4 + q) ^ nq);
                bF[cs][s] = *(const bf16x8*)(sB + slot * 16);
            }
        }

        // ---- pass 1: same-class column sums (over all real rows, incl self) ----
        float samec[4] = {0.f, 0.f, 0.f, 0.f};
        for (int ti = 0; ti < ntile; ++ti) {
            f32x4 acc[4][4];
            #pragma unroll
            for (int rs = 0; rs < 4; ++rs)
                #pragma unroll
                for (int cs = 0; cs < 4; ++cs) acc[rs][cs] = (f32x4){0.f, 0.f, 0.f, 0.f};
            #pragma unroll
            for (int s = 0; s < 4; ++s) {
                bf16x8 aF[4];
                #pragma unroll
                for (int rs = 0; rs < 4; ++rs) {
                    int rA = ti * 64 + rs * 16 + nq;
                    int slot = rA * 16 + ((s * 4 + q) ^ nq);
                    aF[rs] = *(const bf16x8*)(sB + slot * 16);
                }
                #pragma unroll
                for (int rs = 0; rs < 4; ++rs)
                    #pragma unroll
                    for (int cs = 0; cs < 4; ++cs)
                        acc[rs][cs] = __builtin_amdgcn_mfma_f32_16x16x32_bf16(
                            aF[rs], bF[cs][s], acc[rs][cs], 0, 0, 0);
            }
            #pragma unroll
            for (int cs = 0; cs < 4; ++cs)
                #pragma unroll
                for (int rs = 0; rs < 4; ++rs)
                    #pragma unroll
                    for (int rr = 0; rr < 4; ++rr) {
                        int p = ti * 64 + rs * 16 + q * 4 + rr;
                        float e = exp2f(acc[rs][cs][rr] * K2);
                        samec[cs] += (p < twoM) ? e : 0.0f;
                    }
        }
        // complete column sums across q groups
        #pragma unroll
        for (int cs = 0; cs < 4; ++cs) {
            samec[cs] += __shfl_xor(samec[cs], 16, 64);
            samec[cs] += __shfl_xor(samec[cs], 32, 64);
        }
        // neg[col] = full[col] - same[col]
        float negc[4];
        #pragma unroll
        for (int cs = 0; cs < 4; ++cs) {
            int qq = tj * 64 + cs * 16 + nq;
            negc[cs] = s_full[qq < twoM ? qq : 0] - samec[cs];
        }

        // ---- pass 2: recompute acc (bit-identical) and emit terms ----
        for (int ti = 0; ti < ntile; ++ti) {
            f32x4 acc[4][4];
            #pragma unroll
            for (int rs = 0; rs < 4; ++rs)
                #pragma unroll
                for (int cs = 0; cs < 4; ++cs) acc[rs][cs] = (f32x4){0.f, 0.f, 0.f, 0.f};
            #pragma unroll
            for (int s = 0; s < 4; ++s) {
                bf16x8 aF[4];
                #pragma unroll
                for (int rs = 0; rs < 4; ++rs) {
                    int rA = ti * 64 + rs * 16 + nq;
                    int slot = rA * 16 + ((s * 4 + q) ^ nq);
                    aF[rs] = *(const bf16x8*)(sB + slot * 16);
                }
                #pragma unroll
                for (int rs = 0; rs < 4; ++rs)
                    #pragma unroll
                    for (int cs = 0; cs < 4; ++cs)
                        acc[rs][cs] = __builtin_amdgcn_mfma_f32_16x16x32_bf16(
                            aF[rs], bF[cs][s], acc[rs][cs], 0, 0, 0);
            }
            #pragma unroll
            for (int cs = 0; cs < 4; ++cs) {
                int qq = tj * 64 + cs * 16 + nq;
                #pragma unroll
                for (int rs = 0; rs < 4; ++rs)
                    #pragma unroll
                    for (int rr = 0; rr < 4; ++rr) {
                        int p = ti * 64 + rs * 16 + q * 4 + rr;
                        bool valid = (p < twoM) && (qq < twoM) && (p != qq);
                        float logit = acc[rs][cs][rr] * SCALE;
                        float e = __expf(logit);
                        float term = logit - __logf(negc[cs] + e);
                        partial += valid ? term : 0.0f;
                    }
            }
        }
    }

    #pragma unroll
    for (int mm = 32; mm >= 1; mm >>= 1) partial += __shfl_xor(partial, mm, 64);
    if (lane == 0) red[wave] = partial;
    __syncthreads();
    if (tid == 0) {
        atomicAdd(total, red[0] + red[1] + red[2] + red[3]);
        __threadfence();
        unsigned prev = __hip_atomic_fetch_add(done, 1u, __ATOMIC_ACQ_REL,
                                               __HIP_MEMORY_SCOPE_AGENT);
        if (prev == (unsigned)(NCLS - 1)) {
            float tot = __hip_atomic_load(total, __ATOMIC_ACQUIRE,
                                          __HIP_MEMORY_SCOPE_AGENT);
            out[0] = -tot * (1.0f / (float)NN);
        }
    }
}

extern "C" void kernel_launch(void* const* d_in, const int* in_sizes, int n_in,
                              void* d_out, int out_size, void* d_ws, size_t ws_size,
                              hipStream_t stream) {
    const float* feat = (const float*)d_in[0];
    const int* labels = (const int*)d_in[1];
    unsigned short* nf = (unsigned short*)d_ws;
    float* part     = (float*)((char*)d_ws + (size_t)NN * DD * sizeof(unsigned short));
    float* total    = part + (size_t)NPART * NN; // 1
    unsigned* done  = (unsigned*)(total + 1);    // 1
    int* counts     = (int*)(done + 1);          // 100
    int* offsets    = counts + NCLS;             // 101
    int* classIdx   = offsets + NCLS + 1;        // 4096
    float* out = (float*)d_out;

    hipLaunchKernelGGL(k_norm_bucket, dim3(NN / 4 + 1), dim3(256), 0, stream,
                       feat, nf, (unsigned*)total, labels, counts, offsets, classIdx);
    hipLaunchKernelGGL(k_negsum, dim3(NSEG), dim3(256), 0, stream, nf, part);
    hipLaunchKernelGGL(k_loss, dim3(NCLS), dim3(256), 0, stream,
                       nf, counts, offsets, classIdx, part, total, done, out);
}

// Round 8
// 110.139 us; speedup vs baseline: 1.3673x; 1.0490x over previous
//
#include <hip/hip_runtime.h>

// SupConLoss on MI355X. features: [4096, 2, 128] fp32; labels: [4096] int; out: 1 f32.
//
// R14 changes vs R13 (decomposition: negsum 44.8->36 via symmetry WORKED, but
// R12-style k_loss regressed 7.5->19.5 us -- 1 wave per col-tile, 2 serial
// passes, no TLP at 100 blocks):
//  - k_loss: both passes distribute (ti,tj) pairs over ALL 4 waves (R9's pp
//    loop). Pass S: acc -> exp2 -> same-class col sums into LDS s_same[]
//    (shfl reduce + LDS atomicAdd). Barrier. Pass T: recompute acc (same
//    wave, same order -> bit-identical; self-term cancels exactly as in
//    R12/R13) and emit logit - log(full - same + e).
//  - k_negsum: whole 128x128 B-tile staged in ONE shot (32 KB, 8
//    global_load_lds per thread, single barrier) -- removes one
//    vmcnt(0)+barrier drain per block, doubles load overlap depth.
//    Same XOR swizzle (row&15 invariant to half offset).
//  - norm+bucket unchanged.
//
// ws layout: nf (2 MB) | part 64x8192 f32 (2 MB) | total f32 | done u32
//            | counts 100 | offsets 101 | classIdx 4096

#define BATCH 4096
#define NN    8192
#define DD    128
#define NCLS  100
#define MAXR  192
#define NPART 64          // one partial per 128-row/col block
#define NBLK  64          // 8192 / 128
#define NSEG  2080        // 64*65/2 upper-triangle tiles
#define SCALE (1.0f / 0.07f)
#define K2    (SCALE * 1.44269504088896340736f)   // SCALE * log2(e)

typedef __attribute__((ext_vector_type(8))) short bf16x8;
typedef __attribute__((ext_vector_type(4))) float f32x4;

__device__ __forceinline__ unsigned short f2bf(float f) {
    unsigned u = __float_as_uint(f);
    u += 0x7FFF + ((u >> 16) & 1);
    return (unsigned short)(u >> 16);
}

// blocks 0..2047: normalize; block 0 also zeroes total/done
// block 2048:     label bucketing (histogram, offsets, member scatter)
__global__ __launch_bounds__(256) void k_norm_bucket(
        const float* __restrict__ feat, unsigned short* __restrict__ nf,
        unsigned* __restrict__ zeroTD,
        const int* __restrict__ labels, int* __restrict__ counts,
        int* __restrict__ offsets, int* __restrict__ classIdx) {
    __shared__ int cnt[NCLS], off[NCLS], cur[NCLS];

    if (blockIdx.x < NN / 4) {
        if (blockIdx.x == 0 && threadIdx.x < 2) zeroTD[threadIdx.x] = 0u;  // total, done
        int wave = threadIdx.x >> 6, lane = threadIdx.x & 63;
        int row = blockIdx.x * 4 + wave;
        int v = row >> 12, b = row & (BATCH - 1);
        const float2* src = (const float2*)(feat + ((size_t)b * 2 + v) * DD);
        float2 x = src[lane];
        float ss = x.x * x.x + x.y * x.y;
        #pragma unroll
        for (int m = 32; m >= 1; m >>= 1) ss += __shfl_xor(ss, m, 64);
        float inv = rsqrtf(ss);
        ushort2 o;
        o.x = f2bf(x.x * inv);
        o.y = f2bf(x.y * inv);
        ((ushort2*)(nf + (size_t)row * DD))[lane] = o;
        return;
    }

    // ---- bucket path (single block, 256 threads) ----
    int tid = threadIdx.x;
    if (tid < NCLS) cnt[tid] = 0;
    __syncthreads();
    for (int b = tid; b < BATCH; b += 256) atomicAdd(&cnt[labels[b]], 1);
    __syncthreads();
    if (tid < NCLS) {
        int a = 0;
        for (int k = 0; k < tid; ++k) a += cnt[k];   // lockstep LDS broadcast
        off[tid] = a;
        cur[tid] = 0;
        counts[tid] = cnt[tid];
        offsets[tid] = a;
    }
    if (tid == 0) offsets[NCLS] = BATCH;
    __syncthreads();
    for (int b = tid; b < BATCH; b += 256) {
        int l = labels[b];
        int p = atomicAdd(&cur[l], 1);
        classIdx[off[l] + p] = b;
    }
}

// ---- pass 1 (symmetric, atomic-free, label-free): tile (bi,bj), bi<=bj.
// Whole 128x128 B-tile staged in one shot (single barrier).
// Row sums of exp(logit) -> part[bj][rows of bi]; col sums -> part[bi][cols
// of bj] (off-diag only; diag col sums are symmetric duplicates).
__global__ __launch_bounds__(256, 4) void k_negsum(
        const unsigned short* __restrict__ nf,
        float* __restrict__ part) {
    __shared__ __attribute__((aligned(16))) unsigned short smem[128 * 128];  // 32 KB
    __shared__ float s_colacc[128];                                          // 512 B

    // triangular unrank: g -> (bi, bj)
    int g = blockIdx.x, bi = 0;
    for (;;) {
        int n = NBLK - bi;
        if (g < n) break;
        g -= n; ++bi;
    }
    int bj = bi + g;
    bool diag = (bi == bj);

    int tid = threadIdx.x, wave = tid >> 6, lane = tid & 63;
    int q = lane >> 4, nq = lane & 15;
    int rowW = bi * 128 + wave * 32;           // wave's 32-row base
    const bf16x8* nfv = (const bf16x8*)nf;

    if (tid < 128) s_colacc[tid] = 0.0f;

    // stage the whole B tile: 2048 16B chunks, XOR-swizzled
    #pragma unroll
    for (int it = 0; it < 8; ++it) {
        int widx = wave * 8 + it;              // 0..31
        int chunkIdx = widx * 64 + lane;       // 0..2047
        int r = chunkIdx >> 4, cS = chunkIdx & 15;
        int cG = cS ^ (r & 15);
        const unsigned short* gp = nf + (size_t)(bj * 128 + r) * DD + cG * 8;
        unsigned short* lp = smem + (size_t)widx * 512;
        __builtin_amdgcn_global_load_lds(
            (const __attribute__((address_space(1))) void*)gp,
            (__attribute__((address_space(3))) void*)lp, 16, 0, 0);
    }

    // A frags (8): direct global (L2-resident), once per block
    bf16x8 aF[2][4];
    #pragma unroll
    for (int rs = 0; rs < 2; ++rs) {
        int r = rowW + rs * 16 + nq;
        #pragma unroll
        for (int s = 0; s < 4; ++s) aF[rs][s] = nfv[r * 16 + s * 4 + q];
    }
    float rowsum[2][4];
    #pragma unroll
    for (int rs = 0; rs < 2; ++rs)
        #pragma unroll
        for (int rr = 0; rr < 4; ++rr) rowsum[rs][rr] = 0.0f;

    __syncthreads();                           // tile + colacc ready
    const char* sB = (const char*)smem;

    #pragma unroll
    for (int ht = 0; ht < 2; ++ht) {
        f32x4 acc[2][4];
        #pragma unroll
        for (int rs = 0; rs < 2; ++rs)
            #pragma unroll
            for (int cs = 0; cs < 4; ++cs) acc[rs][cs] = (f32x4){0.f, 0.f, 0.f, 0.f};
        #pragma unroll
        for (int s = 0; s < 4; ++s) {
            bf16x8 bF[4];
            #pragma unroll
            for (int cs = 0; cs < 4; ++cs) {
                int rB = ht * 64 + cs * 16 + nq;             // tile row 0..127
                int slot = rB * 16 + ((s * 4 + q) ^ nq);
                bF[cs] = *(const bf16x8*)(sB + slot * 16);
            }
            #pragma unroll
            for (int rs = 0; rs < 2; ++rs)
                #pragma unroll
                for (int cs = 0; cs < 4; ++cs)
                    acc[rs][cs] = __builtin_amdgcn_mfma_f32_16x16x32_bf16(
                        aF[rs][s], bF[cs], acc[rs][cs], 0, 0, 0);
        }

        // C/D layout: col = lane&15, row = (lane>>4)*4 + reg
        #pragma unroll
        for (int cs = 0; cs < 4; ++cs) {
            float colsum = 0.0f;
            #pragma unroll
            for (int rs = 0; rs < 2; ++rs)
                #pragma unroll
                for (int rr = 0; rr < 4; ++rr) {
                    float e = exp2f(acc[rs][cs][rr] * K2);
                    rowsum[rs][rr] += e;
                    colsum += e;
                }
            if (!diag) {
                colsum += __shfl_xor(colsum, 16, 64);
                colsum += __shfl_xor(colsum, 32, 64);
                if (q == 0) atomicAdd(&s_colacc[ht * 64 + cs * 16 + nq], colsum);
            }
        }
    }

    // row partials: reduce over nq groups, store to part[bj][row]
    #pragma unroll
    for (int rs = 0; rs < 2; ++rs)
        #pragma unroll
        for (int rr = 0; rr < 4; ++rr) {
            float vsum = rowsum[rs][rr];
            vsum += __shfl_xor(vsum, 1, 64);
            vsum += __shfl_xor(vsum, 2, 64);
            vsum += __shfl_xor(vsum, 4, 64);
            vsum += __shfl_xor(vsum, 8, 64);
            if (nq == 0) part[(size_t)bj * NN + rowW + rs * 16 + q * 4 + rr] = vsum;
        }

    // col partials: part[bi][cols of bj]
    if (!diag) {
        __syncthreads();                       // all waves' LDS adds done
        if (tid < 128) part[(size_t)bi * NN + bj * 128 + tid] = s_colacc[tid];
    }
}

// ---- pass 2: per-class MFMA, 4-wave-balanced 2-phase.
// Phase S: same-class col sums (incl. self) -> LDS s_same[].
// Phase T: recompute acc (bit-identical) and emit terms with
// neg[j] = full[j] - same[j]. ----
__global__ __launch_bounds__(256) void k_loss(
        const unsigned short* __restrict__ nf,
        const int* __restrict__ counts, const int* __restrict__ offsets,
        const int* __restrict__ classIdx,
        const float* __restrict__ part,
        float* __restrict__ total, unsigned* __restrict__ done,
        float* __restrict__ out) {
    __shared__ __attribute__((aligned(16))) unsigned short s_feat[MAXR * 128]; // 48 KB
    __shared__ int s_rows[MAXR];
    __shared__ float s_full[MAXR];
    __shared__ float s_same[MAXR];
    __shared__ float red[4];

    int c = blockIdx.x;
    int m = counts[c], off = offsets[c];
    int twoM = 2 * m; if (twoM > MAXR) twoM = MAXR;
    int tid = threadIdx.x, wave = tid >> 6, lane = tid & 63;
    int q = lane >> 4, nq = lane & 15;

    for (int r = tid; r < twoM; r += 256) {
        int b = classIdx[off + (r < m ? r : r - m)];
        int row = (r < m) ? b : b + BATCH;
        s_rows[r] = row;
        float ns = 0.0f;
        #pragma unroll 16
        for (int kp = 0; kp < NPART; ++kp) ns += part[(size_t)kp * NN + row];
        s_full[r] = ns;
    }
    if (tid < MAXR) s_same[tid] = 0.0f;
    __syncthreads();    // s_rows ready before gather staging

    int ntile = (twoM + 63) >> 6;            // 1..3
    int nchunk = ntile * 64 * 16;
    // gather-stage rows (clamped: r>=twoM duplicates last row; masked later)
    for (int widx = wave; widx * 64 < nchunk; widx += 4) {
        int chunkIdx = widx * 64 + lane;
        int r = chunkIdx >> 4, cS = chunkIdx & 15;
        int cG = cS ^ (r & 15);
        int rc = r < twoM ? r : twoM - 1;
        const unsigned short* gp = nf + (size_t)s_rows[rc] * DD + cG * 8;
        unsigned short* lp = s_feat + (size_t)widx * 512;
        __builtin_amdgcn_global_load_lds(
            (const __attribute__((address_space(1))) void*)gp,
            (__attribute__((address_space(3))) void*)lp, 16, 0, 0);
    }
    __syncthreads();

    const char* sB = (const char*)s_feat;
    int npairs = ntile * ntile;

    // ---- phase S: same-class column sums (over all real rows, incl self) ----
    for (int pp = wave; pp < npairs; pp += 4) {
        int ti = pp / ntile, tj = pp - ti * ntile;
        f32x4 acc[4][4];
        #pragma unroll
        for (int rs = 0; rs < 4; ++rs)
            #pragma unroll
            for (int cs = 0; cs < 4; ++cs) acc[rs][cs] = (f32x4){0.f, 0.f, 0.f, 0.f};
        #pragma unroll
        for (int s = 0; s < 4; ++s) {
            bf16x8 aF[4], bF[4];
            #pragma unroll
            for (int rs = 0; rs < 4; ++rs) {
                int rA = ti * 64 + rs * 16 + nq;
                aF[rs] = *(const bf16x8*)(sB + (rA * 16 + ((s * 4 + q) ^ nq)) * 16);
            }
            #pragma unroll
            for (int cs = 0; cs < 4; ++cs) {
                int rB = tj * 64 + cs * 16 + nq;
                bF[cs] = *(const bf16x8*)(sB + (rB * 16 + ((s * 4 + q) ^ nq)) * 16);
            }
            #pragma unroll
            for (int rs = 0; rs < 4; ++rs)
                #pragma unroll
                for (int cs = 0; cs < 4; ++cs)
                    acc[rs][cs] = __builtin_amdgcn_mfma_f32_16x16x32_bf16(
                        aF[rs], bF[cs], acc[rs][cs], 0, 0, 0);
        }
        #pragma unroll
        for (int cs = 0; cs < 4; ++cs) {
            int qq = tj * 64 + cs * 16 + nq;
            float colsum = 0.0f;
            #pragma unroll
            for (int rs = 0; rs < 4; ++rs)
                #pragma unroll
                for (int rr = 0; rr < 4; ++rr) {
                    int p = ti * 64 + rs * 16 + q * 4 + rr;
                    float e = exp2f(acc[rs][cs][rr] * K2);
                    colsum += (p < twoM) ? e : 0.0f;
                }
            colsum += __shfl_xor(colsum, 16, 64);
            colsum += __shfl_xor(colsum, 32, 64);
            if (q == 0 && qq < twoM) atomicAdd(&s_same[qq], colsum);
        }
    }
    __syncthreads();

    // ---- phase T: recompute acc (bit-identical) and emit terms ----
    float partial = 0.0f;
    for (int pp = wave; pp < npairs; pp += 4) {
        int ti = pp / ntile, tj = pp - ti * ntile;
        f32x4 acc[4][4];
        #pragma unroll
        for (int rs = 0; rs < 4; ++rs)
            #pragma unroll
            for (int cs = 0; cs < 4; ++cs) acc[rs][cs] = (f32x4){0.f, 0.f, 0.f, 0.f};
        #pragma unroll
        for (int s = 0; s < 4; ++s) {
            bf16x8 aF[4], bF[4];
            #pragma unroll
            for (int rs = 0; rs < 4; ++rs) {
                int rA = ti * 64 + rs * 16 + nq;
                aF[rs] = *(const bf16x8*)(sB + (rA * 16 + ((s * 4 + q) ^ nq)) * 16);
            }
            #pragma unroll
            for (int cs = 0; cs < 4; ++cs) {
                int rB = tj * 64 + cs * 16 + nq;
                bF[cs] = *(const bf16x8*)(sB + (rB * 16 + ((s * 4 + q) ^ nq)) * 16);
            }
            #pragma unroll
            for (int rs = 0; rs < 4; ++rs)
                #pragma unroll
                for (int cs = 0; cs < 4; ++cs)
                    acc[rs][cs] = __builtin_amdgcn_mfma_f32_16x16x32_bf16(
                        aF[rs], bF[cs], acc[rs][cs], 0, 0, 0);
        }
        #pragma unroll
        for (int cs = 0; cs < 4; ++cs) {
            int qq = tj * 64 + cs * 16 + nq;
            float negc = (qq < twoM) ? (s_full[qq] - s_same[qq]) : 1.0f;
            #pragma unroll
            for (int rs = 0; rs < 4; ++rs)
                #pragma unroll
                for (int rr = 0; rr < 4; ++rr) {
                    int p = ti * 64 + rs * 16 + q * 4 + rr;
                    bool valid = (p < twoM) && (qq < twoM) && (p != qq);
                    float logit = acc[rs][cs][rr] * SCALE;
                    float e = __expf(logit);
                    float term = logit - __logf(negc + e);
                    partial += valid ? term : 0.0f;
                }
        }
    }

    #pragma unroll
    for (int mm = 32; mm >= 1; mm >>= 1) partial += __shfl_xor(partial, mm, 64);
    if (lane == 0) red[wave] = partial;
    __syncthreads();
    if (tid == 0) {
        atomicAdd(total, red[0] + red[1] + red[2] + red[3]);
        __threadfence();
        unsigned prev = __hip_atomic_fetch_add(done, 1u, __ATOMIC_ACQ_REL,
                                               __HIP_MEMORY_SCOPE_AGENT);
        if (prev == (unsigned)(NCLS - 1)) {
            float tot = __hip_atomic_load(total, __ATOMIC_ACQUIRE,
                                          __HIP_MEMORY_SCOPE_AGENT);
            out[0] = -tot * (1.0f / (float)NN);
        }
    }
}

extern "C" void kernel_launch(void* const* d_in, const int* in_sizes, int n_in,
                              void* d_out, int out_size, void* d_ws, size_t ws_size,
                              hipStream_t stream) {
    const float* feat = (const float*)d_in[0];
    const int* labels = (const int*)d_in[1];
    unsigned short* nf = (unsigned short*)d_ws;
    float* part     = (float*)((char*)d_ws + (size_t)NN * DD * sizeof(unsigned short));
    float* total    = part + (size_t)NPART * NN; // 1
    unsigned* done  = (unsigned*)(total + 1);    // 1
    int* counts     = (int*)(done + 1);          // 100
    int* offsets    = counts + NCLS;             // 101
    int* classIdx   = offsets + NCLS + 1;        // 4096
    float* out = (float*)d_out;

    hipLaunchKernelGGL(k_norm_bucket, dim3(NN / 4 + 1), dim3(256), 0, stream,
                       feat, nf, (unsigned*)total, labels, counts, offsets, classIdx);
    hipLaunchKernelGGL(k_negsum, dim3(NSEG), dim3(256), 0, stream, nf, part);
    hipLaunchKernelGGL(k_loss, dim3(NCLS), dim3(256), 0, stream,
                       nf, counts, offsets, classIdx, part, total, done, out);
}

// Round 9
// 105.876 us; speedup vs baseline: 1.4223x; 1.0403x over previous
//
#include <hip/hip_runtime.h>

// SupConLoss on MI355X. features: [4096, 2, 128] fp32; labels: [4096] int; out: 1 f32.
//
// R15 changes vs R14 (110.1; negsum ~30 OK but 2-phase loss ~20 us -- the
// label-free-negsum/subtract-in-loss trade doubles loss MFMA and never pays):
//  - k_negsum: label mask RESTORED in the epilogue (s_clab LDS + rlab regs,
//    cmp+cndmask per element). Keeps R14's single-stage whole-tile staging,
//    symmetric upper-triangle grid, atomic-free/zero-free partial stores.
//    Masked partials make self-pairs vanish (equal labels) -- same semantics
//    as R6/R9 which passed.
//  - k_loss: back to R9's SINGLE-pass structure (pp pairs over 4 waves, one
//    MFMA pass, term = logit - log(ns[col] + e)); no phase S/T, no recompute.
//  - part layout transposed to part[row][64]: negsum scatters a few stores;
//    loss gathers 64 partials per row as 16 contiguous float4 loads.
//
// ws layout: nf (2 MB) | part 8192x64 f32 (2 MB) | total f32 | done u32
//            | counts 100 | offsets 101 | classIdx 4096

#define BATCH 4096
#define NN    8192
#define DD    128
#define NCLS  100
#define MAXR  192
#define NPART 64          // partials per row (one per 128-col block)
#define NBLK  64          // 8192 / 128
#define NSEG  2080        // 64*65/2 upper-triangle tiles
#define SCALE (1.0f / 0.07f)
#define K2    (SCALE * 1.44269504088896340736f)   // SCALE * log2(e)

typedef __attribute__((ext_vector_type(8))) short bf16x8;
typedef __attribute__((ext_vector_type(4))) float f32x4;

__device__ __forceinline__ unsigned short f2bf(float f) {
    unsigned u = __float_as_uint(f);
    u += 0x7FFF + ((u >> 16) & 1);
    return (unsigned short)(u >> 16);
}

// blocks 0..2047: normalize; block 0 also zeroes total/done
// block 2048:     label bucketing (histogram, offsets, member scatter)
__global__ __launch_bounds__(256) void k_norm_bucket(
        const float* __restrict__ feat, unsigned short* __restrict__ nf,
        unsigned* __restrict__ zeroTD,
        const int* __restrict__ labels, int* __restrict__ counts,
        int* __restrict__ offsets, int* __restrict__ classIdx) {
    __shared__ int cnt[NCLS], off[NCLS], cur[NCLS];

    if (blockIdx.x < NN / 4) {
        if (blockIdx.x == 0 && threadIdx.x < 2) zeroTD[threadIdx.x] = 0u;  // total, done
        int wave = threadIdx.x >> 6, lane = threadIdx.x & 63;
        int row = blockIdx.x * 4 + wave;
        int v = row >> 12, b = row & (BATCH - 1);
        const float2* src = (const float2*)(feat + ((size_t)b * 2 + v) * DD);
        float2 x = src[lane];
        float ss = x.x * x.x + x.y * x.y;
        #pragma unroll
        for (int m = 32; m >= 1; m >>= 1) ss += __shfl_xor(ss, m, 64);
        float inv = rsqrtf(ss);
        ushort2 o;
        o.x = f2bf(x.x * inv);
        o.y = f2bf(x.y * inv);
        ((ushort2*)(nf + (size_t)row * DD))[lane] = o;
        return;
    }

    // ---- bucket path (single block, 256 threads) ----
    int tid = threadIdx.x;
    if (tid < NCLS) cnt[tid] = 0;
    __syncthreads();
    for (int b = tid; b < BATCH; b += 256) atomicAdd(&cnt[labels[b]], 1);
    __syncthreads();
    if (tid < NCLS) {
        int a = 0;
        for (int k = 0; k < tid; ++k) a += cnt[k];   // lockstep LDS broadcast
        off[tid] = a;
        cur[tid] = 0;
        counts[tid] = cnt[tid];
        offsets[tid] = a;
    }
    if (tid == 0) offsets[NCLS] = BATCH;
    __syncthreads();
    for (int b = tid; b < BATCH; b += 256) {
        int l = labels[b];
        int p = atomicAdd(&cur[l], 1);
        classIdx[off[l] + p] = b;
    }
}

// ---- pass 1 (symmetric, atomic-free, MASKED): tile (bi,bj), bi<=bj.
// Whole 128x128 B-tile staged in one shot (single barrier).
// Masked row sums -> part[row][bj] (rows of bi); masked col sums ->
// part[bj*128+c][bi] (off-diag only; diag col sums = row sums by symmetry).
// Equal-label pairs (incl. self) contribute 0 -> exact reference negmask.
__global__ __launch_bounds__(256, 4) void k_negsum(
        const unsigned short* __restrict__ nf,
        const int* __restrict__ labels,
        float* __restrict__ part) {
    __shared__ __attribute__((aligned(16))) unsigned short smem[128 * 128];  // 32 KB
    __shared__ float s_colacc[128];                                          // 512 B
    __shared__ int s_clab[128];                                              // 512 B

    // triangular unrank: g -> (bi, bj)
    int g = blockIdx.x, bi = 0;
    for (;;) {
        int n = NBLK - bi;
        if (g < n) break;
        g -= n; ++bi;
    }
    int bj = bi + g;
    bool diag = (bi == bj);

    int tid = threadIdx.x, wave = tid >> 6, lane = tid & 63;
    int q = lane >> 4, nq = lane & 15;
    int rowW = bi * 128 + wave * 32;           // wave's 32-row base
    const bf16x8* nfv = (const bf16x8*)nf;

    if (tid < 128) {
        s_colacc[tid] = 0.0f;
        s_clab[tid] = labels[(bj * 128 + tid) & (BATCH - 1)];
    }

    // stage the whole B tile: 2048 16B chunks, XOR-swizzled
    #pragma unroll
    for (int it = 0; it < 8; ++it) {
        int widx = wave * 8 + it;              // 0..31
        int chunkIdx = widx * 64 + lane;       // 0..2047
        int r = chunkIdx >> 4, cS = chunkIdx & 15;
        int cG = cS ^ (r & 15);
        const unsigned short* gp = nf + (size_t)(bj * 128 + r) * DD + cG * 8;
        unsigned short* lp = smem + (size_t)widx * 512;
        __builtin_amdgcn_global_load_lds(
            (const __attribute__((address_space(1))) void*)gp,
            (__attribute__((address_space(3))) void*)lp, 16, 0, 0);
    }

    // A frags (8) + row labels: direct global (L2-resident), once per block
    bf16x8 aF[2][4];
    #pragma unroll
    for (int rs = 0; rs < 2; ++rs) {
        int r = rowW + rs * 16 + nq;
        #pragma unroll
        for (int s = 0; s < 4; ++s) aF[rs][s] = nfv[r * 16 + s * 4 + q];
    }
    int rlab[2][4];
    float rowsum[2][4];
    #pragma unroll
    for (int rs = 0; rs < 2; ++rs)
        #pragma unroll
        for (int rr = 0; rr < 4; ++rr) {
            rlab[rs][rr] = labels[(rowW + rs * 16 + q * 4 + rr) & (BATCH - 1)];
            rowsum[rs][rr] = 0.0f;
        }

    __syncthreads();                           // tile + colacc + clab ready
    const char* sB = (const char*)smem;

    #pragma unroll
    for (int ht = 0; ht < 2; ++ht) {
        f32x4 acc[2][4];
        #pragma unroll
        for (int rs = 0; rs < 2; ++rs)
            #pragma unroll
            for (int cs = 0; cs < 4; ++cs) acc[rs][cs] = (f32x4){0.f, 0.f, 0.f, 0.f};
        #pragma unroll
        for (int s = 0; s < 4; ++s) {
            bf16x8 bF[4];
            #pragma unroll
            for (int cs = 0; cs < 4; ++cs) {
                int rB = ht * 64 + cs * 16 + nq;             // tile row 0..127
                int slot = rB * 16 + ((s * 4 + q) ^ nq);
                bF[cs] = *(const bf16x8*)(sB + slot * 16);
            }
            #pragma unroll
            for (int rs = 0; rs < 2; ++rs)
                #pragma unroll
                for (int cs = 0; cs < 4; ++cs)
                    acc[rs][cs] = __builtin_amdgcn_mfma_f32_16x16x32_bf16(
                        aF[rs][s], bF[cs], acc[rs][cs], 0, 0, 0);
        }

        // C/D layout: col = lane&15, row = (lane>>4)*4 + reg
        #pragma unroll
        for (int cs = 0; cs < 4; ++cs) {
            int cl = s_clab[ht * 64 + cs * 16 + nq];
            float colsum = 0.0f;
            #pragma unroll
            for (int rs = 0; rs < 2; ++rs)
                #pragma unroll
                for (int rr = 0; rr < 4; ++rr) {
                    float e = exp2f(acc[rs][cs][rr] * K2);
                    float ev = (rlab[rs][rr] != cl) ? e : 0.0f;
                    rowsum[rs][rr] += ev;
                    colsum += ev;
                }
            if (!diag) {
                colsum += __shfl_xor(colsum, 16, 64);
                colsum += __shfl_xor(colsum, 32, 64);
                if (q == 0) atomicAdd(&s_colacc[ht * 64 + cs * 16 + nq], colsum);
            }
        }
    }

    // row partials: reduce over nq groups, store to part[row][bj]
    #pragma unroll
    for (int rs = 0; rs < 2; ++rs)
        #pragma unroll
        for (int rr = 0; rr < 4; ++rr) {
            float vsum = rowsum[rs][rr];
            vsum += __shfl_xor(vsum, 1, 64);
            vsum += __shfl_xor(vsum, 2, 64);
            vsum += __shfl_xor(vsum, 4, 64);
            vsum += __shfl_xor(vsum, 8, 64);
            if (nq == 0)
                part[(size_t)(rowW + rs * 16 + q * 4 + rr) * NPART + bj] = vsum;
        }

    // col partials: part[col of bj][bi]
    if (!diag) {
        __syncthreads();                       // all waves' LDS adds done
        if (tid < 128) part[(size_t)(bj * 128 + tid) * NPART + bi] = s_colacc[tid];
    }
}

// ---- pass 2: per-class MFMA, single pass (R9 structure), 4-wave pp loop.
// ns[col] already label-masked; term = logit - log(ns + e). ----
__global__ __launch_bounds__(256) void k_loss(
        const unsigned short* __restrict__ nf,
        const int* __restrict__ counts, const int* __restrict__ offsets,
        const int* __restrict__ classIdx,
        const float* __restrict__ part,
        float* __restrict__ total, unsigned* __restrict__ done,
        float* __restrict__ out) {
    __shared__ __attribute__((aligned(16))) unsigned short s_feat[MAXR * 128]; // 48 KB
    __shared__ int s_rows[MAXR];
    __shared__ float s_ns[MAXR];
    __shared__ float red[4];

    int c = blockIdx.x;
    int m = counts[c], off = offsets[c];
    int twoM = 2 * m; if (twoM > MAXR) twoM = MAXR;
    int tid = threadIdx.x, wave = tid >> 6, lane = tid & 63;
    int q = lane >> 4, nq = lane & 15;

    for (int r = tid; r < twoM; r += 256) {
        int b = classIdx[off + (r < m ? r : r - m)];
        int row = (r < m) ? b : b + BATCH;
        s_rows[r] = row;
        const float4* pv = (const float4*)(part + (size_t)row * NPART);
        float4 a0 = (float4){0.f, 0.f, 0.f, 0.f};
        #pragma unroll
        for (int kp = 0; kp < NPART / 4; ++kp) {
            float4 v = pv[kp];
            a0.x += v.x; a0.y += v.y; a0.z += v.z; a0.w += v.w;
        }
        s_ns[r] = a0.x + a0.y + a0.z + a0.w;
    }
    __syncthreads();    // s_rows ready before gather staging

    int ntile = (twoM + 63) >> 6;            // 1..3
    int nchunk = ntile * 64 * 16;
    // gather-stage rows (clamped: r>=twoM duplicates last row; masked later)
    for (int widx = wave; widx * 64 < nchunk; widx += 4) {
        int chunkIdx = widx * 64 + lane;
        int r = chunkIdx >> 4, cS = chunkIdx & 15;
        int cG = cS ^ (r & 15);
        int rc = r < twoM ? r : twoM - 1;
        const unsigned short* gp = nf + (size_t)s_rows[rc] * DD + cG * 8;
        unsigned short* lp = s_feat + (size_t)widx * 512;
        __builtin_amdgcn_global_load_lds(
            (const __attribute__((address_space(1))) void*)gp,
            (__attribute__((address_space(3))) void*)lp, 16, 0, 0);
    }
    __syncthreads();

    const char* sB = (const char*)s_feat;
    float partial = 0.0f;
    int npairs = ntile * ntile;
    for (int pp = wave; pp < npairs; pp += 4) {
        int ti = pp / ntile, tj = pp - ti * ntile;
        bf16x8 aF[4][4];
        #pragma unroll
        for (int rs = 0; rs < 4; ++rs) {
            int rA = ti * 64 + rs * 16 + nq;
            #pragma unroll
            for (int s = 0; s < 4; ++s) {
                int slot = rA * 16 + ((s * 4 + q) ^ nq);
                aF[rs][s] = *(const bf16x8*)(sB + slot * 16);
            }
        }
        f32x4 acc[4][4];
        #pragma unroll
        for (int rs = 0; rs < 4; ++rs)
            #pragma unroll
            for (int cs = 0; cs < 4; ++cs) acc[rs][cs] = (f32x4){0.f, 0.f, 0.f, 0.f};
        #pragma unroll
        for (int s = 0; s < 4; ++s) {
            bf16x8 bF[4];
            #pragma unroll
            for (int cs = 0; cs < 4; ++cs) {
                int rB = tj * 64 + cs * 16 + nq;
                int slot = rB * 16 + ((s * 4 + q) ^ nq);
                bF[cs] = *(const bf16x8*)(sB + slot * 16);
            }
            #pragma unroll
            for (int rs = 0; rs < 4; ++rs)
                #pragma unroll
                for (int cs = 0; cs < 4; ++cs)
                    acc[rs][cs] = __builtin_amdgcn_mfma_f32_16x16x32_bf16(
                        aF[rs][s], bF[cs], acc[rs][cs], 0, 0, 0);
        }
        #pragma unroll
        for (int cs = 0; cs < 4; ++cs) {
            int qq = tj * 64 + cs * 16 + nq;
            float ns = s_ns[qq < twoM ? qq : 0];
            #pragma unroll
            for (int rs = 0; rs < 4; ++rs)
                #pragma unroll
                for (int rr = 0; rr < 4; ++rr) {
                    int p = ti * 64 + rs * 16 + q * 4 + rr;
                    bool valid = (p < twoM) && (qq < twoM) && (p != qq);
                    float logit = acc[rs][cs][rr] * SCALE;
                    float e = __expf(logit);
                    float term = logit - __logf(ns + e);
                    partial += valid ? term : 0.0f;
                }
        }
    }

    #pragma unroll
    for (int mm = 32; mm >= 1; mm >>= 1) partial += __shfl_xor(partial, mm, 64);
    if (lane == 0) red[wave] = partial;
    __syncthreads();
    if (tid == 0) {
        atomicAdd(total, red[0] + red[1] + red[2] + red[3]);
        __threadfence();
        unsigned prev = __hip_atomic_fetch_add(done, 1u, __ATOMIC_ACQ_REL,
                                               __HIP_MEMORY_SCOPE_AGENT);
        if (prev == (unsigned)(NCLS - 1)) {
            float tot = __hip_atomic_load(total, __ATOMIC_ACQUIRE,
                                          __HIP_MEMORY_SCOPE_AGENT);
            out[0] = -tot * (1.0f / (float)NN);
        }
    }
}

extern "C" void kernel_launch(void* const* d_in, const int* in_sizes, int n_in,
                              void* d_out, int out_size, void* d_ws, size_t ws_size,
                              hipStream_t stream) {
    const float* feat = (const float*)d_in[0];
    const int* labels = (const int*)d_in[1];
    unsigned short* nf = (unsigned short*)d_ws;
    float* part     = (float*)((char*)d_ws + (size_t)NN * DD * sizeof(unsigned short));
    float* total    = part + (size_t)NN * NPART; // 1
    unsigned* done  = (unsigned*)(total + 1);    // 1
    int* counts     = (int*)(done + 1);          // 100
    int* offsets    = counts + NCLS;             // 101
    int* classIdx   = offsets + NCLS + 1;        // 4096
    float* out = (float*)d_out;

    hipLaunchKernelGGL(k_norm_bucket, dim3(NN / 4 + 1), dim3(256), 0, stream,
                       feat, nf, (unsigned*)total, labels, counts, offsets, classIdx);
    hipLaunchKernelGGL(k_negsum, dim3(NSEG), dim3(256), 0, stream, nf, labels, part);
    hipLaunchKernelGGL(k_loss, dim3(NCLS), dim3(256), 0, stream,
                       nf, counts, offsets, classIdx, part, total, done, out);
}